// Round 3
// baseline (196.575 us; speedup 1.0000x reference)
//
#include <hip/hip_runtime.h>
#include <math.h>

#define EMA_A 0.99f
#define EMA_B 0.01f
#define THRESH 0.8f
#define EPS_F 1e-8f

#define NBLK2 256   // blocks in k_update
#define RPB   32    // rows per block (M / NBLK2, M = 8192)

// ---------------------------------------------------------------------------
// ws layout (bytes):
//   [0]      int   K
//   [4]      int   filled_final
//   [8]      float sumw
//   [1024]           int   slot_info[M]          (32 KB) -1=untouched else (src<<1)|exists
//   [1024+4M]        float w[M]                  (32 KB)
//   [1024+8M]        float partial1[NBLK2*C]     (2 MB)
//   [1024+8M+4*NBLK2*C] float partial2[NBLK2*C]  (2 MB)
// total ~4.3 MB
// ---------------------------------------------------------------------------

__global__ __launch_bounds__(1024)
void k_scan(const float* __restrict__ conf,
            const float* __restrict__ mem_conf,
            const int* __restrict__ ptr0_p,
            const int* __restrict__ filled0_p,
            int* __restrict__ hdr,
            int* __restrict__ slot_info,
            float* __restrict__ w,
            int B, int M)
{
    const int tid  = threadIdx.x;        // 0..1023
    const int lane = tid & 63;
    const int wave = tid >> 6;           // 0..15

    // init slot_info (ws is poisoned each launch)
    for (int m = tid; m < M; m += 1024) slot_info[m] = -1;

    // load 8 confidences per thread, build high-mask
    const int base_i = tid * 8;
    int mask = 0;
    #pragma unroll
    for (int k = 0; k < 8; ++k) {
        int i = base_i + k;
        float c = (i < B) ? conf[i] : 0.0f;
        mask |= (c > THRESH) ? (1 << k) : 0;
    }
    int cnt = __popc(mask);

    __shared__ int s_cnt[1024];
    __shared__ int s_gbase[64];
    __shared__ int s_scalars[2];     // [0]=K, [1]=filled_final
    s_cnt[tid] = cnt;
    __syncthreads();

    // wave 0 scans 64 groups of 16 threads
    if (tid < 64) {
        int sum16 = 0;
        #pragma unroll
        for (int u = 0; u < 16; ++u) sum16 += s_cnt[tid * 16 + u];
        int v = sum16;
        #pragma unroll
        for (int d = 1; d < 64; d <<= 1) {
            int o = __shfl_up(v, d, 64);
            if (lane >= d) v += o;
        }
        s_gbase[tid] = v - sum16;           // exclusive group base
        if (tid == 63) s_scalars[0] = v;    // K = total high count
    }
    __syncthreads();
    const int K = s_scalars[0];

    // per-thread exclusive prefix of high-count
    int j = s_gbase[tid >> 4];
    for (int u = (tid & ~15); u < tid; ++u) j += s_cnt[u];

    // closed-form 'exists' as a function of write index j (data-independent):
    //   sweep 0: j in [0, L0)      -> p = P0+j,   exists iff p < F0
    //   sweep 1: j in [L0, L0+M)   -> p = j-L0,   exists iff p < F1
    //   sweep 2+:                  -> always exists
    int P0 = ((ptr0_p[0] % M) + M) % M;
    int F0 = filled0_p[0];
    if (F0 < 0) F0 = 0;
    if (F0 > M) F0 = M;
    const int L0 = M - P0;                         // writes in first sweep
    const int F1 = F0 + (M - (P0 > F0 ? P0 : F0)); // filled after first sweep

    #pragma unroll
    for (int k = 0; k < 8; ++k) {
        if (mask & (1 << k)) {
            int exist;
            if (j < L0)          exist = (P0 + j) < F0 ? 1 : 0;
            else if (j < L0 + M) exist = (j - L0) < F1 ? 1 : 0;
            else                 exist = 1;
            int p = (P0 + j) % M;
            slot_info[p] = ((base_i + k) << 1) | exist;
            ++j;
        }
    }

    if (tid == 0) {
        int n0 = K < L0 ? K : L0;
        int e0 = F0 - P0; if (e0 < 0) e0 = 0; if (e0 > n0) e0 = n0;
        int fresh0 = n0 - e0;
        int n1 = K - L0; if (n1 < 0) n1 = 0; if (n1 > M) n1 = M;
        int fresh1 = n1 - F1; if (fresh1 < 0) fresh1 = 0;
        int filled = F0 + fresh0 + fresh1;
        if (filled > M) filled = M;
        s_scalars[1] = filled;
        hdr[0] = K;
        hdr[1] = filled;
    }
    __syncthreads();
    const int filled = s_scalars[1];

    // updated confidences -> weights w[m], and sumw
    float acc = 0.0f;
    for (int m = tid; m < M; m += 1024) {
        int info = slot_info[m];
        float mco = mem_conf[m];
        float mcu;
        if (info >= 0) {
            float c = conf[info >> 1];
            mcu = (info & 1) ? (EMA_A * mco + EMA_B * c) : c;
        } else {
            mcu = mco;
        }
        float wm = (m < filled) ? mcu : 0.0f;
        w[m] = wm;
        acc += wm;
    }
    #pragma unroll
    for (int d = 32; d >= 1; d >>= 1) acc += __shfl_down(acc, d, 64);
    __shared__ float s_red[16];
    if (lane == 0) s_red[wave] = acc;
    __syncthreads();
    if (tid == 0) {
        float s = 0.0f;
        for (int u = 0; u < 16; ++u) s += s_red[u];
        ((float*)hdr)[2] = s;
    }
}

// ---------------------------------------------------------------------------

__device__ __forceinline__ float4 f4_ema(float4 m, float4 f) {
    float4 r;
    r.x = EMA_A * m.x + EMA_B * f.x;
    r.y = EMA_A * m.y + EMA_B * f.y;
    r.z = EMA_A * m.z + EMA_B * f.z;
    r.w = EMA_A * m.w + EMA_B * f.w;
    return r;
}

__global__ __launch_bounds__(512)
void k_update(const float* __restrict__ mem_feat,
              const float* __restrict__ feat,
              const int* __restrict__ slot_info,
              const float* __restrict__ w,
              float* __restrict__ out,
              float* __restrict__ p1,
              float* __restrict__ p2,
              int C)
{
    const int blk = blockIdx.x, tid = threadIdx.x;
    const int c0 = tid * 4;                 // 512 threads x 4 = 2048 = C

    __shared__ int   s_info[RPB];
    __shared__ float s_w[RPB];
    const int row0 = blk * RPB;
    if (tid < RPB) {
        s_info[tid] = slot_info[row0 + tid];
        s_w[tid]    = w[row0 + tid];
    }
    __syncthreads();

    float4 s1 = {0.f, 0.f, 0.f, 0.f};
    float4 s2 = {0.f, 0.f, 0.f, 0.f};

    #pragma unroll 4
    for (int r = 0; r < RPB; ++r) {
        const int m = row0 + r;
        const size_t base = (size_t)m * C;
        float4 mv = *(const float4*)(mem_feat + base + c0);
        const int info = s_info[r];
        float4 x;
        if (info >= 0) {
            float4 fv = *(const float4*)(feat + (size_t)(info >> 1) * C + c0);
            x = (info & 1) ? f4_ema(mv, fv) : fv;
        } else {
            x = mv;
        }
        const float wv = s_w[r];
        s1.x += wv * x.x; s1.y += wv * x.y; s1.z += wv * x.z; s1.w += wv * x.w;
        s2.x += wv * x.x * x.x; s2.y += wv * x.y * x.y;
        s2.z += wv * x.z * x.z; s2.w += wv * x.w * x.w;
        *(float4*)(out + base + c0) = x;
    }
    const size_t pb = (size_t)blk * C;
    *(float4*)(p1 + pb + c0) = s1;
    *(float4*)(p2 + pb + c0) = s2;
}

// ---------------------------------------------------------------------------

__global__ __launch_bounds__(256)
void k_stats(const float* __restrict__ p1,
             const float* __restrict__ p2,
             const float* __restrict__ hdrf,
             float* __restrict__ out,
             int M, int C)
{
    const int cc = threadIdx.x & 31;
    const int chunk = threadIdx.x >> 5;       // 0..7
    const int c = blockIdx.x * 32 + cc;
    double s1 = 0.0, s2 = 0.0;
    for (int bb = 0; bb < 32; ++bb) {
        int b = chunk * 32 + bb;
        s1 += (double)p1[(size_t)b * C + c];
        s2 += (double)p2[(size_t)b * C + c];
    }
    __shared__ double l1[256], l2[256];
    l1[threadIdx.x] = s1;
    l2[threadIdx.x] = s2;
    __syncthreads();
    if (chunk == 0) {
        for (int q = 1; q < 8; ++q) { s1 += l1[cc + 32 * q]; s2 += l2[cc + 32 * q]; }
        double sumw  = (double)hdrf[2];
        double total = sumw + (double)EPS_F;
        double mean  = s1 / total;
        double var   = (s2 - 2.0 * mean * s1 + mean * mean * sumw) / total;
        out[(size_t)M * C + c]       = (float)mean;
        out[(size_t)(M + 1) * C + c] = (float)sqrt(var + (double)EPS_F);
    }
}

// ---------------------------------------------------------------------------

extern "C" void kernel_launch(void* const* d_in, const int* in_sizes, int n_in,
                              void* d_out, int out_size, void* d_ws, size_t ws_size,
                              hipStream_t stream)
{
    const float* features     = (const float*)d_in[0];
    const float* confidence   = (const float*)d_in[1];
    const float* mem_features = (const float*)d_in[2];
    const float* mem_conf     = (const float*)d_in[3];
    const int*   ptr0         = (const int*)d_in[4];
    const int*   filled0      = (const int*)d_in[5];

    const int B = in_sizes[1];          // 8192
    const int M = in_sizes[3];          // 8192
    const int C = in_sizes[0] / B;      // 2048

    char* ws = (char*)d_ws;
    int*   hdr       = (int*)ws;
    int*   slot_info = (int*)(ws + 1024);
    float* w         = (float*)(ws + 1024 + 4 * (size_t)M);
    float* p1        = (float*)(ws + 1024 + 8 * (size_t)M);
    float* p2        = (float*)(ws + 1024 + 8 * (size_t)M + 4 * (size_t)NBLK2 * C);

    float* out = (float*)d_out;

    k_scan<<<1, 1024, 0, stream>>>(confidence, mem_conf, ptr0, filled0,
                                   hdr, slot_info, w, B, M);
    k_update<<<NBLK2, 512, 0, stream>>>(mem_features, features, slot_info, w,
                                        out, p1, p2, C);
    k_stats<<<C / 32, 256, 0, stream>>>(p1, p2, (const float*)hdr, out, M, C);
}

// Round 5
// 185.614 us; speedup vs baseline: 1.0591x; 1.0591x over previous
//
#include <hip/hip_runtime.h>
#include <math.h>

#define EMA_A 0.99f
#define EMA_B 0.01f
#define THRESH 0.8f
#define EPS_F 1e-8f

#define NBLK2 512   // blocks in k_update
#define RPB   16    // rows per block (M / NBLK2, M = 8192)

typedef float fx4 __attribute__((ext_vector_type(4)));   // native vector (nontemporal-store ok)

// ---------------------------------------------------------------------------
// ws layout (bytes):
//   [0]          int   hdr[0]=K, hdr[1]=filled_final
//   [1024]       int   slot_info[M]           (32 KB) -1=untouched else (src<<1)|exists
//   [1024+4M]    float p0[NBLK2]              (2 KB)  per-block sum of w
//   [65536]      float p1[NBLK2*C]            (4 MB)  per-block sum of w*x
//   [65536+4MB]  float p2[NBLK2*C]            (4 MB)  per-block sum of w*x*x
// total ~8.5 MB
// ---------------------------------------------------------------------------

__global__ __launch_bounds__(1024)
void k_scan(const float* __restrict__ conf,
            const int* __restrict__ ptr0_p,
            const int* __restrict__ filled0_p,
            int* __restrict__ hdr,
            int* __restrict__ slot_info,
            int B, int M)
{
    const int tid  = threadIdx.x;        // 0..1023
    const int lane = tid & 63;

    // init slot_info (ws is poisoned each launch)
    for (int m = tid; m < M; m += 1024) slot_info[m] = -1;

    // load 8 confidences per thread, build high-mask
    const int base_i = tid * 8;
    int mask = 0;
    #pragma unroll
    for (int k = 0; k < 8; ++k) {
        int i = base_i + k;
        float c = (i < B) ? conf[i] : 0.0f;
        mask |= (c > THRESH) ? (1 << k) : 0;
    }
    int cnt = __popc(mask);

    __shared__ int s_cnt[1024];
    __shared__ int s_gbase[64];
    s_cnt[tid] = cnt;
    __syncthreads();

    // wave 0 scans 64 groups of 16 threads
    if (tid < 64) {
        int sum16 = 0;
        #pragma unroll
        for (int u = 0; u < 16; ++u) sum16 += s_cnt[tid * 16 + u];
        int v = sum16;
        #pragma unroll
        for (int d = 1; d < 64; d <<= 1) {
            int o = __shfl_up(v, d, 64);
            if (lane >= d) v += o;
        }
        s_gbase[tid] = v - sum16;           // exclusive group base
        if (tid == 63) hdr[0] = v;          // K
    }
    __syncthreads();
    const int K = hdr[0];

    // per-thread exclusive prefix of high-count
    int j = s_gbase[tid >> 4];
    for (int u = (tid & ~15); u < tid; ++u) j += s_cnt[u];

    // closed-form 'exists' as a function of write index j (data-independent):
    //   sweep 0: j in [0, L0)      -> p = P0+j, exists iff p < F0
    //   sweep 1: j in [L0, L0+M)   -> p = j-L0, exists iff p < F1
    //   sweep 2+:                  -> always exists
    int P0 = ((ptr0_p[0] % M) + M) % M;
    int F0 = filled0_p[0];
    if (F0 < 0) F0 = 0;
    if (F0 > M) F0 = M;
    const int L0 = M - P0;                         // writes in first sweep
    const int F1 = F0 + (M - (P0 > F0 ? P0 : F0)); // filled after first sweep

    #pragma unroll
    for (int k = 0; k < 8; ++k) {
        if (mask & (1 << k)) {
            int exist;
            if (j < L0)          exist = (P0 + j) < F0 ? 1 : 0;
            else if (j < L0 + M) exist = (j - L0) < F1 ? 1 : 0;
            else                 exist = 1;
            int p = (P0 + j) % M;
            slot_info[p] = ((base_i + k) << 1) | exist;
            ++j;
        }
    }

    if (tid == 0) {
        int n0 = K < L0 ? K : L0;
        int e0 = F0 - P0; if (e0 < 0) e0 = 0; if (e0 > n0) e0 = n0;
        int fresh0 = n0 - e0;
        int n1 = K - L0; if (n1 < 0) n1 = 0; if (n1 > M) n1 = M;
        int fresh1 = n1 - F1; if (fresh1 < 0) fresh1 = 0;
        int filled = F0 + fresh0 + fresh1;
        if (filled > M) filled = M;
        hdr[1] = filled;
    }
}

// ---------------------------------------------------------------------------

__global__ __launch_bounds__(512)
void k_update(const float* __restrict__ mem_feat,
              const float* __restrict__ feat,
              const float* __restrict__ conf,
              const float* __restrict__ mem_conf,
              const int* __restrict__ slot_info,
              const int* __restrict__ hdr,
              float* __restrict__ out,
              float* __restrict__ p0,
              float* __restrict__ p1,
              float* __restrict__ p2,
              int C)
{
    const int blk = blockIdx.x, tid = threadIdx.x;
    const int c0 = tid * 4;                 // 512 threads x 4 = 2048 = C

    __shared__ int   s_info[RPB];
    __shared__ float s_w[RPB];
    const int row0 = blk * RPB;
    if (tid < RPB) {
        const int m = row0 + tid;
        const int info = slot_info[m];
        const int filled = hdr[1];
        const float mco = mem_conf[m];
        float mcu = mco;
        if (info >= 0) {
            float c = conf[info >> 1];
            mcu = (info & 1) ? (EMA_A * mco + EMA_B * c) : c;
        }
        s_info[tid] = info;
        s_w[tid]    = (m < filled) ? mcu : 0.0f;
    }
    __syncthreads();
    if (tid == 0) {
        float s = 0.0f;
        #pragma unroll
        for (int r = 0; r < RPB; ++r) s += s_w[r];
        p0[blk] = s;
    }

    fx4 s1 = {0.f, 0.f, 0.f, 0.f};
    fx4 s2 = {0.f, 0.f, 0.f, 0.f};

    #pragma unroll 4
    for (int r = 0; r < RPB; ++r) {
        const int m = row0 + r;
        const size_t base = (size_t)m * C;
        const int info = s_info[r];          // block-uniform -> no divergence
        fx4 x;
        if (info < 0) {
            x = *(const fx4*)(mem_feat + base + c0);
        } else if (info & 1) {
            fx4 mv = *(const fx4*)(mem_feat + base + c0);
            fx4 fv = *(const fx4*)(feat + (size_t)(info >> 1) * C + c0);
            x = EMA_A * mv + EMA_B * fv;
        } else {                             // fresh overwrite: mem value unused
            x = *(const fx4*)(feat + (size_t)(info >> 1) * C + c0);
        }
        const float wv = s_w[r];
        s1 += wv * x;
        s2 += wv * x * x;
        __builtin_nontemporal_store(x, (fx4*)(out + base + c0));
    }
    const size_t pb = (size_t)blk * C;
    *(fx4*)(p1 + pb + c0) = s1;
    *(fx4*)(p2 + pb + c0) = s2;
}

// ---------------------------------------------------------------------------

__global__ __launch_bounds__(256)
void k_stats(const float* __restrict__ p0,
             const float* __restrict__ p1,
             const float* __restrict__ p2,
             float* __restrict__ out,
             int M, int C)
{
    const int tid = threadIdx.x;

    // deterministic sumw reduce over NBLK2 per-block partials
    __shared__ float s_sw[4];
    float sw = 0.0f;
    for (int i = tid; i < NBLK2; i += 256) sw += p0[i];
    #pragma unroll
    for (int d = 32; d >= 1; d >>= 1) sw += __shfl_down(sw, d, 64);
    if ((tid & 63) == 0) s_sw[tid >> 6] = sw;
    __syncthreads();

    const int cc = tid & 31;
    const int chunk = tid >> 5;               // 0..7, NBLK2/8 partial-rows each
    const int c = blockIdx.x * 32 + cc;
    double s1 = 0.0, s2 = 0.0;
    for (int bb = 0; bb < NBLK2 / 8; ++bb) {
        int b = chunk * (NBLK2 / 8) + bb;
        s1 += (double)p1[(size_t)b * C + c];
        s2 += (double)p2[(size_t)b * C + c];
    }
    __shared__ double l1[256], l2[256];
    l1[tid] = s1;
    l2[tid] = s2;
    __syncthreads();
    if (chunk == 0) {
        for (int q = 1; q < 8; ++q) { s1 += l1[cc + 32 * q]; s2 += l2[cc + 32 * q]; }
        double sumw  = (double)(s_sw[0] + s_sw[1] + s_sw[2] + s_sw[3]);
        double total = sumw + (double)EPS_F;
        double mean  = s1 / total;
        double var   = (s2 - 2.0 * mean * s1 + mean * mean * sumw) / total;
        out[(size_t)M * C + c]       = (float)mean;
        out[(size_t)(M + 1) * C + c] = (float)sqrt(var + (double)EPS_F);
    }
}

// ---------------------------------------------------------------------------

extern "C" void kernel_launch(void* const* d_in, const int* in_sizes, int n_in,
                              void* d_out, int out_size, void* d_ws, size_t ws_size,
                              hipStream_t stream)
{
    const float* features     = (const float*)d_in[0];
    const float* confidence   = (const float*)d_in[1];
    const float* mem_features = (const float*)d_in[2];
    const float* mem_conf     = (const float*)d_in[3];
    const int*   ptr0         = (const int*)d_in[4];
    const int*   filled0      = (const int*)d_in[5];

    const int B = in_sizes[1];          // 8192
    const int M = in_sizes[3];          // 8192
    const int C = in_sizes[0] / B;      // 2048

    char* ws = (char*)d_ws;
    int*   hdr       = (int*)ws;
    int*   slot_info = (int*)(ws + 1024);
    float* p0        = (float*)(ws + 1024 + 4 * (size_t)M);
    float* p1        = (float*)(ws + 65536);
    float* p2        = (float*)(ws + 65536 + 4 * (size_t)NBLK2 * C);

    float* out = (float*)d_out;

    k_scan<<<1, 1024, 0, stream>>>(confidence, ptr0, filled0, hdr, slot_info, B, M);
    k_update<<<NBLK2, 512, 0, stream>>>(mem_features, features, confidence, mem_conf,
                                        slot_info, hdr, out, p0, p1, p2, C);
    k_stats<<<C / 32, 256, 0, stream>>>(p0, p1, p2, out, M, C);
}